// Round 8
// baseline (348.658 us; speedup 1.0000x reference)
//
#include <hip/hip_runtime.h>
#include <hip/hip_fp16.h>

// Persistent 256-block kernel (1 block/CU forced by ~156 KB LDS).
// Rows 2b,2b+1 of all 64 Omega_t cached ONCE in LDS as fp16 (validated
// R4-R8, absmax 0.0078). NTAY=3 Taylor terms of expm(A)@v.
//
// Exchange (fence-free): relaxed agent-scope 8-byte atomics only.
// TWO floats per word, tag in low-2 mantissa bits of float0. 256 words
// per round, ONE PER 64B LINE (spread; R13 proved packing regresses).
// Buffers fixed: buf0 = h1, buf1/2/3 = T1/T2/T3. Tags = s&3 (h1(s) tag
// s&3, published at T3(s-1) tail). Skew induction: block B overwrites
// buf_k word B for step s only after fully gathering the prior round;
// chain implies every block finished reading the old value (distance-4
// rounds / period-4-step tag reuse safe). d_ws re-poisoned 0xAA each
// launch (poison low2=2 != startup tag 0).
//
// FAILED (counters): R12 890us atomicAdd reduction (MALL RMW serialization).
// R13 292us packed exchange (publisher line contention). R14/R15/R16
// 1145-1202us register-file W1 (allocator pins 128 VGPR, spills 1GB/disp;
// waves_per_eu(2,2) ignored). ABANDONED.
//
// R17 (verified, 234us disp): h1(s+1) published in T3 tail -> h1 round is
// a poll-hit, not an RT. Deferred stores (llog). ILP'd MLP.
// R18 (this round):
//  - h1 gather OVERLAPPED with the Taylor window: waves 1-4 poll buf0 tag
//    (s+1)&3 DURING wave0's T1..T3 (pre-sleep(64) then sleep(8) sweeps;
//    ~20GB/s poll traffic, negligible). Detection hides under wave0's
//    tail+argmax -> h1 leaves the critical chain entirely.
//    Race-free: single-location coherence makes the only observable tags
//    {s&3 (stale, no match), (s+1)&3 (fresh)}; no block can run 4 steps
//    ahead (gather-gated); MLP's h1_s reads are 3 barriers before rewrite.
//  - h2-combine FUSED into L3 stage (per-wave broadcast recompute of
//    h2[i]; q3 is wave-uniform -> conflict-free). L3 partials go to a new
//    redq[] (WAR-safe vs redp). Barriers/step 7 -> 5.

#define NBLK 256
#define NTHR 512
#define NSTEP 20
#define NTAY 3
#define RBUF 4

typedef unsigned long long ull;

// word i (i<256) of exchange buffer buf: 64 B apart (spread layout)
#define XW(buf, i) (X + ((((buf) << 8) + (i)) << 3))

__device__ __forceinline__ float wredsum(float p) {
#pragma unroll
  for (int off = 32; off > 0; off >>= 1) p += __shfl_xor(p, off, 64);
  return p;
}

__device__ __forceinline__ void wredsum2(float& p0, float& p1) {
#pragma unroll
  for (int off = 32; off > 0; off >>= 1) {
    float t0 = __shfl_xor(p0, off, 64);
    float t1 = __shfl_xor(p1, off, 64);
    p0 += t0;
    p1 += t1;
  }
}

__device__ __forceinline__ void publish2(ull* w, float v0, float v1, unsigned int tag2) {
  unsigned int u0 = (__float_as_uint(v0) & ~3u) | tag2;
  ull x = (ull)u0 | ((ull)__float_as_uint(v1) << 32);
  __hip_atomic_store(w, x, __ATOMIC_RELAXED, __HIP_MEMORY_SCOPE_AGENT);
}

__device__ __forceinline__ float2 poll2(ull* w, unsigned int tag2) {
  int it = 0;
  for (;;) {
    ull x = __hip_atomic_load(w, __ATOMIC_RELAXED, __HIP_MEMORY_SCOPE_AGENT);
    if ((unsigned int)(x & 3u) == tag2) {
      float2 r;
      r.x = __uint_as_float((unsigned int)x);
      r.y = __uint_as_float((unsigned int)(x >> 32));
      return r;
    }
    if (it == 0)      __builtin_amdgcn_s_sleep(1);
    else if (it == 1) __builtin_amdgcn_s_sleep(2);
    else              __builtin_amdgcn_s_sleep(4);
    if (it < 2) ++it;
  }
}

// lane-quad poll: 4 words (64 B apart) -> 8 floats; all 4 loads kept in
// flight per retry iteration (hand-unrolled, no runtime-indexed arrays).
__device__ __forceinline__ void poll8(ull* w0, unsigned int tg, float* o) {
  ull x0 = 0, x1 = 0, x2 = 0, x3 = 0;
  bool g0 = false, g1 = false, g2 = false, g3 = false;
  int it = 0;
  for (;;) {
    if (!g0) { ull x = __hip_atomic_load(w0,      __ATOMIC_RELAXED, __HIP_MEMORY_SCOPE_AGENT); if ((unsigned int)(x & 3u) == tg) { x0 = x; g0 = true; } }
    if (!g1) { ull x = __hip_atomic_load(w0 + 8,  __ATOMIC_RELAXED, __HIP_MEMORY_SCOPE_AGENT); if ((unsigned int)(x & 3u) == tg) { x1 = x; g1 = true; } }
    if (!g2) { ull x = __hip_atomic_load(w0 + 16, __ATOMIC_RELAXED, __HIP_MEMORY_SCOPE_AGENT); if ((unsigned int)(x & 3u) == tg) { x2 = x; g2 = true; } }
    if (!g3) { ull x = __hip_atomic_load(w0 + 24, __ATOMIC_RELAXED, __HIP_MEMORY_SCOPE_AGENT); if ((unsigned int)(x & 3u) == tg) { x3 = x; g3 = true; } }
    if (g0 && g1 && g2 && g3) break;
    if (it == 0)      __builtin_amdgcn_s_sleep(1);
    else if (it == 1) __builtin_amdgcn_s_sleep(2);
    else              __builtin_amdgcn_s_sleep(4);
    if (it < 2) ++it;
  }
  o[0] = __uint_as_float((unsigned int)x0); o[1] = __uint_as_float((unsigned int)(x0 >> 32));
  o[2] = __uint_as_float((unsigned int)x1); o[3] = __uint_as_float((unsigned int)(x1 >> 32));
  o[4] = __uint_as_float((unsigned int)x2); o[5] = __uint_as_float((unsigned int)(x2 >> 32));
  o[6] = __uint_as_float((unsigned int)x3); o[7] = __uint_as_float((unsigned int)(x3 >> 32));
}

__global__ __launch_bounds__(NTHR) void petri_kernel(
    const float* __restrict__ vsrc, const float* __restrict__ vtgt,
    const float* __restrict__ omg,  const float* __restrict__ W1,
    const float* __restrict__ b1,   const float* __restrict__ W2,
    const float* __restrict__ b2,   const float* __restrict__ W3,
    const float* __restrict__ b3,   const float* __restrict__ gum,
    ull* __restrict__ X, float* __restrict__ out) {
  __shared__ __half2 oh[64 * 512];   // 128 KB: {row2b[j], row2b+1[j]} per t
  __shared__ __align__(16) float A0_s[512];
  __shared__ __align__(16) float A1_s[512];
  __shared__ __align__(16) float v_loc[512];
  __shared__ float tgt_s[512];
  __shared__ float w1c_s[1024];      // W1 column b (both halves)
  __shared__ float gum_s[NSTEP * 64];
  __shared__ float b2_s[128], b3_s[64];
  __shared__ float soft_s[64], h1_s[256];
  __shared__ float redp[512];        // L2 partials
  __shared__ float redq[512];        // L3 partials (WAR-safe vs redp)
  __shared__ float llog[NSTEP * 64]; // deferred logits
  __shared__ float rf8[8];
  __shared__ int   ri8[8];
  __shared__ float cB_s[1];
  __shared__ int   bc[1];

  const int b = blockIdx.x, tid = threadIdx.x;
  const int wv = tid >> 6, ln = tid & 63;

  v_loc[tid] = vsrc[tid];
  tgt_s[tid] = vtgt[tid];
  w1c_s[tid] = W1[tid * 256 + b];
  w1c_s[tid + 512] = W1[(tid + 512) * 256 + b];
  for (int i = tid; i < NSTEP * 64; i += NTHR) gum_s[i] = gum[i];
  if (tid >= NTHR - 128) {
    int j = tid - (NTHR - 128);
    b2_s[j] = b2[j];
    if (j < 64) b3_s[j] = b3[j];
  }
  // W2 column slice in registers: thread (o=tid&127,q=tid>>7) holds
  // W2[(q*64+i)*128+o], i=0..63
  float w2r[64];
  {
    const int o = tid & 127, q = tid >> 7;
    const float* p = W2 + ((q << 6) * 128) + o;
#pragma unroll
    for (int i = 0; i < 64; ++i) w2r[i] = p[i * 128];
  }
  // W3 slice: thread (o=tid&63,q=tid>>6) holds W3[(q*16+i)*64+o], i=0..15
  float w3r[16];
  {
    const int o = tid & 63, q = tid >> 6;
    const float* p = W3 + ((q << 4) * 64) + o;
#pragma unroll
    for (int i = 0; i < 16; ++i) w3r[i] = p[i * 64];
  }
  // Omega rows 2b,2b+1 -> LDS fp16, float4-vectorized
  {
    const int tq = tid >> 7;            // 0..3 : t within group of 4
    const int c4 = (tid & 127) << 2;    // col 0..508 step 4
    const float* rp = omg + (b << 10) + c4;
#pragma unroll 4
    for (int g = 0; g < 16; ++g) {
      const int t = (g << 2) + tq;
      const float* p = rp + t * 262144;
      const float4 f0 = *(const float4*)(p);        // row 2b
      const float4 f1 = *(const float4*)(p + 512);  // row 2b+1
      __half2* dst = oh + t * 512 + c4;
      dst[0] = __floats2half2_rn(f0.x, f1.x);
      dst[1] = __floats2half2_rn(f0.y, f1.y);
      dst[2] = __floats2half2_rn(f0.z, f1.z);
      dst[3] = __floats2half2_rn(f0.w, f1.w);
    }
  }
  __syncthreads();

  // cB = b1[b] + dot(tgt, W1_bot[:,b])  -- off the per-step critical path
  {
    float p = tgt_s[tid] * w1c_s[tid + 512];
    p = wredsum(p);
    if (ln == 0) rf8[wv] = p;
    __syncthreads();
    if (tid == 0) {
      float a = b1[b];
      for (int q = 0; q < 8; ++q) a += rf8[q];
      cB_s[0] = a;
    }
    __syncthreads();
  }

  // target argmax (identical in every block), first-index tie-break
  int tgtIdx;
  {
    float v = tgt_s[tid]; int ix = tid;
#pragma unroll
    for (int off = 32; off > 0; off >>= 1) {
      float ov = __shfl_xor(v, off, 64); int oi = __shfl_xor(ix, off, 64);
      if (ov > v || (ov == v && oi < ix)) { v = ov; ix = oi; }
    }
    if (ln == 0) { rf8[wv] = v; ri8[wv] = ix; }
    __syncthreads();
    if (tid == 0) {
      float bv = rf8[0]; int bix = ri8[0];
      for (int q = 1; q < 8; ++q)
        if (rf8[q] > bv || (rf8[q] == bv && ri8[q] < bix)) { bv = rf8[q]; bix = ri8[q]; }
      bc[0] = bix;
    }
    __syncthreads();
    tgtIdx = bc[0];
    __syncthreads();
  }

  // wave0 register state: lane l owns vector elems 8l..8l+7 (= exchange
  // words 4l..4l+3) and the matching W1-top column slice.
  float vreg[8], w1t[8];
  if (wv == 0) {
    const int l8 = ln << 3;
#pragma unroll
    for (int k = 0; k < 8; ++k) { vreg[k] = v_loc[l8 + k]; w1t[k] = w1c_s[l8 + k]; }
    // startup: publish h1 of step 0 (buf0, tag 0)
    float p = 0.f;
#pragma unroll
    for (int k = 0; k < 8; ++k) p = fmaf(vreg[k], w1t[k], p);
    p = wredsum(p);
    if (ln == 0) {
      float h = fmaxf(p + cB_s[0], 0.f);
      publish2(XW(0, b), h, h, 0u);
    }
  }
  // startup gather of h1(0)
  if (tid < 256) h1_s[tid] = poll2(XW(0, tid), 0u).x;
  __syncthreads();

  int d = 0;
  int nAct = 0;  // number of active steps (uniform across blocks/threads)

  for (int s = 0; s < NSTEP; ++s) {
    if (d) continue;  // frozen (uniform across blocks); epilogue zero-fills
    nAct = s + 1;
    const unsigned int tgS = (unsigned int)(s & 3);

    // ---- L2 partials from h1_s (register weights) ----
    {
      const int q = tid >> 7;
      const float* hp = h1_s + (q << 6);
      float a0 = 0.f, a1 = 0.f, a2 = 0.f, a3 = 0.f;
#pragma unroll
      for (int i = 0; i < 64; i += 4) {
        a0 = fmaf(hp[i],     w2r[i],     a0);
        a1 = fmaf(hp[i + 1], w2r[i + 1], a1);
        a2 = fmaf(hp[i + 2], w2r[i + 2], a2);
        a3 = fmaf(hp[i + 3], w2r[i + 3], a3);
      }
      redp[tid] = (a0 + a1) + (a2 + a3);
    }
    __syncthreads();

    // ---- fused h2-combine + L3 partials (R18) ----
    // Thread (o3=tid&63, q3=wv): recompute h2[i] for i in q3*16..+15 via
    // wave-uniform broadcast reads of redp (conflict-free), fma into acc.
    {
      const int q3 = wv;
      const int base = q3 << 4;
      float a0 = 0.f, a1 = 0.f;
#pragma unroll
      for (int k = 0; k < 16; k += 2) {
        const int i0 = base + k, i1 = base + k + 1;
        const float h20 = fmaxf(redp[i0] + redp[i0 + 128] + redp[i0 + 256] + redp[i0 + 384] + b2_s[i0], 0.f);
        const float h21 = fmaxf(redp[i1] + redp[i1 + 128] + redp[i1 + 256] + redp[i1 + 384] + b2_s[i1], 0.f);
        a0 = fmaf(h20, w3r[k],     a0);
        a1 = fmaf(h21, w3r[k + 1], a1);
      }
      redq[tid] = a0 + a1;
    }
    __syncthreads();

    // ---- logits + gumbel-softmax (wave0's 64 lanes) ----
    if (tid < 64) {
      float a = b3_s[tid];
#pragma unroll
      for (int q = 0; q < 8; ++q) a += redq[tid + (q << 6)];
      float lg = a + gum_s[s * 64 + tid];  // TAU = 1
      float mx = lg;
#pragma unroll
      for (int off = 32; off > 0; off >>= 1) mx = fmaxf(mx, __shfl_xor(mx, off, 64));
      float e = __expf(lg - mx);
      float sm = e;
#pragma unroll
      for (int off = 32; off > 0; off >>= 1) sm += __shfl_xor(sm, off, 64);
      soft_s[tid] = e / sm;
      llog[s * 64 + tid] = a;  // deferred logits
    }
    __syncthreads();

    // ---- mix 2 rows of A from LDS fp16 ----
    {
      float a0 = 0.f, a1 = 0.f, c0 = 0.f, c1 = 0.f;
#pragma unroll 8
      for (int t = 0; t < 64; t += 2) {
        float2 xy0 = __half22float2(oh[t * 512 + tid]);
        float2 xy1 = __half22float2(oh[(t + 1) * 512 + tid]);
        float s0 = soft_s[t], s1 = soft_s[t + 1];
        a0 = fmaf(s0, xy0.x, a0);
        c0 = fmaf(s0, xy0.y, c0);
        a1 = fmaf(s1, xy1.x, a1);
        c1 = fmaf(s1, xy1.y, c1);
      }
      A0_s[tid] = a0 + a1;
      A1_s[tid] = c0 + c1;
    }
    __syncthreads();

    // ---- Taylor T1..T3 (wave0 solo) with h1(s+1) tail publish;
    //      waves 1-4 overlap-poll h1(s+1) (R18) ----
    if (wv == 0) {
      const int l8 = ln << 3;
      const float4 a00 = *(const float4*)(A0_s + l8);      // A row 2b
      const float4 a01 = *(const float4*)(A0_s + l8 + 4);
      const float4 a10 = *(const float4*)(A1_s + l8);      // A row 2b+1
      const float4 a11 = *(const float4*)(A1_s + l8 + 4);
      const float vb0 = v_loc[b << 1], vb1 = v_loc[(b << 1) + 1];
      float wreg[8];
#pragma unroll
      for (int k = 0; k < 8; ++k) wreg[k] = vreg[k];
      float acc0 = 0.f, acc1 = 0.f;
#pragma unroll
      for (int n = 1; n <= NTAY; ++n) {
        float p0 = 0.f, p1 = 0.f;
        p0 = fmaf(a00.x, wreg[0], p0); p0 = fmaf(a00.y, wreg[1], p0);
        p0 = fmaf(a00.z, wreg[2], p0); p0 = fmaf(a00.w, wreg[3], p0);
        p0 = fmaf(a01.x, wreg[4], p0); p0 = fmaf(a01.y, wreg[5], p0);
        p0 = fmaf(a01.z, wreg[6], p0); p0 = fmaf(a01.w, wreg[7], p0);
        p1 = fmaf(a10.x, wreg[0], p1); p1 = fmaf(a10.y, wreg[1], p1);
        p1 = fmaf(a10.z, wreg[2], p1); p1 = fmaf(a10.w, wreg[3], p1);
        p1 = fmaf(a11.x, wreg[4], p1); p1 = fmaf(a11.y, wreg[5], p1);
        p1 = fmaf(a11.z, wreg[6], p1); p1 = fmaf(a11.w, wreg[7], p1);
        wredsum2(p0, p1);
        if (ln == 0) {
          float s0, s1;
          if (n == 1) {
            s0 = p0; s1 = p1;
            acc0 = vb0 + s0; acc1 = vb1 + s1;
          } else {
            const float inv = (n == 2) ? 0.5f : (1.0f / 3.0f);
            s0 = p0 * inv; s1 = p1 * inv;
            acc0 += s0; acc1 += s1;
          }
          const float q0 = (n < NTAY) ? s0 : acc0;  // last round: vnew
          const float q1 = (n < NTAY) ? s1 : acc1;
          publish2(XW(n, b), q0, q1, tgS);          // buf n, tag s&3
        }
        poll8(XW(n, (ln << 2)), tgS, wreg);
      }
      // h1(s+1) tail publish: buf0, tag (s+1)&3. Safe by induction.
      if (s + 1 < NSTEP) {
        float ph = 0.f;
#pragma unroll
        for (int k = 0; k < 8; ++k) ph = fmaf(wreg[k], w1t[k], ph);
        ph = wredsum(ph);
        if (ln == 0) {
          float h = fmaxf(ph + cB_s[0], 0.f);
          publish2(XW(0, b), h, h, (unsigned int)((s + 1) & 3));
        }
      }
      // vnew -> regs + LDS; solo argmax; done flag
#pragma unroll
      for (int k = 0; k < 8; ++k) vreg[k] = wreg[k];
      *(float4*)(v_loc + l8)     = make_float4(wreg[0], wreg[1], wreg[2], wreg[3]);
      *(float4*)(v_loc + l8 + 4) = make_float4(wreg[4], wreg[5], wreg[6], wreg[7]);
      float mv = wreg[0]; int mi = l8;
#pragma unroll
      for (int k = 1; k < 8; ++k) if (wreg[k] > mv) { mv = wreg[k]; mi = l8 + k; }
#pragma unroll
      for (int off = 32; off > 0; off >>= 1) {
        float ov = __shfl_xor(mv, off, 64); int oi = __shfl_xor(mi, off, 64);
        if (ov > mv || (ov == mv && oi < mi)) { mv = ov; mi = oi; }
      }
      if (ln == 0) bc[0] = (mi == tgtIdx) ? 1 : 0;
    } else if (wv <= 4) {
      // overlap-poll h1(s+1) during the Taylor window (R18). Published by
      // each block's T3 tail ~7us from now: pre-sleep then coarse sweeps.
      if (s + 1 < NSTEP) {
        const int w = tid - 64;
        ull* addr = XW(0, w);
        const unsigned int tgh = (unsigned int)((s + 1) & 3);
        __builtin_amdgcn_s_sleep(64);   // ~1.7us: skip most of T1's window
        for (;;) {
          ull x = __hip_atomic_load(addr, __ATOMIC_RELAXED, __HIP_MEMORY_SCOPE_AGENT);
          if ((unsigned int)(x & 3u) == tgh) {
            h1_s[w] = __uint_as_float((unsigned int)x);
            break;
          }
          __builtin_amdgcn_s_sleep(8);  // ~213ns sweeps
        }
      }
    }
    __syncthreads();
    if (bc[0]) d = 1;
  }

  // ---- epilogue: all global writes (block 0 only) ----
  if (b == 0) {
    out[tid] = v_loc[tid];
    for (int i = tid; i < NSTEP * 64; i += NTHR)
      out[512 + i] = (i < nAct * 64) ? llog[i] : 0.0f;
  }
}

extern "C" void kernel_launch(void* const* d_in, const int* in_sizes, int n_in,
                              void* d_out, int out_size, void* d_ws, size_t ws_size,
                              hipStream_t stream) {
  (void)in_sizes; (void)n_in; (void)out_size; (void)ws_size;
  petri_kernel<<<dim3(NBLK), dim3(NTHR), 0, stream>>>(
      (const float*)d_in[0], (const float*)d_in[1], (const float*)d_in[2],
      (const float*)d_in[3], (const float*)d_in[4], (const float*)d_in[5],
      (const float*)d_in[6], (const float*)d_in[7], (const float*)d_in[8],
      (const float*)d_in[9], (ull*)d_ws, (float*)d_out);
}

// Round 9
// 332.160 us; speedup vs baseline: 1.0497x; 1.0497x over previous
//
#include <hip/hip_runtime.h>
#include <hip/hip_fp16.h>

// Persistent 256-block kernel (1 block/CU forced by ~155 KB LDS).
// Rows 2b,2b+1 of all 64 Omega_t cached ONCE in LDS as fp16 (validated
// R4-R8, absmax 0.0078). NTAY=3 Taylor terms of expm(A)@v.
//
// Exchange (fence-free): relaxed agent-scope 8-byte atomics only.
// TWO floats per word, tag in low-2 mantissa bits of float0. 256 words
// per round, ONE PER 64B LINE (spread). 4 rotating buffers: buf0 = h1,
// buf1/2/3 = T1/T2/T3; tags s&3. Skew induction: overwrite only after
// fully gathering the prior round -> distance-4/period-4-step reuse safe.
// Poison 0xAA low2=2 != startup tag 0.
//
// FAILED (counters): R12 890us atomicAdd reduction (MALL RMW serial).
// R13 292us packed exchange (publisher line contention; poller txn count
//   is layout-invariant). R14/R15/R16 1145-1202us register W1 (allocator
//   pins 128 VGPR, 1GB/disp scratch; waves_per_eu ignored). R18 267us
//   overlap-polled h1 (+256 polled words/block concurrent with Taylor
//   window -> +1.7us/step).
//
// MODEL (R13+R18 triangulation): POLL PRESSURE SETS RT LATENCY. poll8
// sweeps 256 words/block per ~0.8us -> 65536 txns/sweep device-wide
// (~5 TB/s at MALL); publishes queue behind polls -> RT 2.3us vs ~1us
// intrinsic. First two sweeps (~0.7us, ~1.5us) are near-certain misses.
//
// R17 (verified best, 234us): h1 published in T3 tail -> h1 round is a
// poll-hit; deferred stores; ILP'd MLP.
// R19 (this round): R17 + PHASE-ALIGNED poll8 ONLY: pre-sleep(40)
// (~1.07us) before first load, then sleep(4) sweeps. First check samples
// ~1.6-1.8us = the visibility window -> detection no later, wait-phase
// traffic ~3x lower. Decisive test of the pressure model: null result
// (>=230us) => RT is intrinsic+spread => structure converged.

#define NBLK 256
#define NTHR 512
#define NSTEP 20
#define NTAY 3
#define RBUF 4

typedef unsigned long long ull;

// word i (i<256) of exchange buffer buf: 64 B apart (spread layout)
#define XW(buf, i) (X + ((((buf) << 8) + (i)) << 3))

__device__ __forceinline__ float wredsum(float p) {
#pragma unroll
  for (int off = 32; off > 0; off >>= 1) p += __shfl_xor(p, off, 64);
  return p;
}

__device__ __forceinline__ void wredsum2(float& p0, float& p1) {
#pragma unroll
  for (int off = 32; off > 0; off >>= 1) {
    float t0 = __shfl_xor(p0, off, 64);
    float t1 = __shfl_xor(p1, off, 64);
    p0 += t0;
    p1 += t1;
  }
}

__device__ __forceinline__ void publish2(ull* w, float v0, float v1, unsigned int tag2) {
  unsigned int u0 = (__float_as_uint(v0) & ~3u) | tag2;
  ull x = (ull)u0 | ((ull)__float_as_uint(v1) << 32);
  __hip_atomic_store(w, x, __ATOMIC_RELAXED, __HIP_MEMORY_SCOPE_AGENT);
}

__device__ __forceinline__ float2 poll2(ull* w, unsigned int tag2) {
  int it = 0;
  for (;;) {
    ull x = __hip_atomic_load(w, __ATOMIC_RELAXED, __HIP_MEMORY_SCOPE_AGENT);
    if ((unsigned int)(x & 3u) == tag2) {
      float2 r;
      r.x = __uint_as_float((unsigned int)x);
      r.y = __uint_as_float((unsigned int)(x >> 32));
      return r;
    }
    if (it == 0)      __builtin_amdgcn_s_sleep(1);
    else if (it == 1) __builtin_amdgcn_s_sleep(2);
    else              __builtin_amdgcn_s_sleep(4);
    if (it < 2) ++it;
  }
}

// lane-quad poll: 4 words (64 B apart) -> 8 floats; all 4 loads kept in
// flight per retry iteration. R19: pre-sleep(40) (~1.07us) before the
// first issue -- publishes cannot be visible earlier (min RT > 1us), so
// the old 0.7us/1.5us sweeps were pure wasted MALL transactions that
// queued ahead of everyone's publishes. Steady sweeps at sleep(4).
__device__ __forceinline__ void poll8(ull* w0, unsigned int tg, float* o) {
  ull x0 = 0, x1 = 0, x2 = 0, x3 = 0;
  bool g0 = false, g1 = false, g2 = false, g3 = false;
  __builtin_amdgcn_s_sleep(40);   // ~1.07us phase-align (R19)
  for (;;) {
    if (!g0) { ull x = __hip_atomic_load(w0,      __ATOMIC_RELAXED, __HIP_MEMORY_SCOPE_AGENT); if ((unsigned int)(x & 3u) == tg) { x0 = x; g0 = true; } }
    if (!g1) { ull x = __hip_atomic_load(w0 + 8,  __ATOMIC_RELAXED, __HIP_MEMORY_SCOPE_AGENT); if ((unsigned int)(x & 3u) == tg) { x1 = x; g1 = true; } }
    if (!g2) { ull x = __hip_atomic_load(w0 + 16, __ATOMIC_RELAXED, __HIP_MEMORY_SCOPE_AGENT); if ((unsigned int)(x & 3u) == tg) { x2 = x; g2 = true; } }
    if (!g3) { ull x = __hip_atomic_load(w0 + 24, __ATOMIC_RELAXED, __HIP_MEMORY_SCOPE_AGENT); if ((unsigned int)(x & 3u) == tg) { x3 = x; g3 = true; } }
    if (g0 && g1 && g2 && g3) break;
    __builtin_amdgcn_s_sleep(4);
  }
  o[0] = __uint_as_float((unsigned int)x0); o[1] = __uint_as_float((unsigned int)(x0 >> 32));
  o[2] = __uint_as_float((unsigned int)x1); o[3] = __uint_as_float((unsigned int)(x1 >> 32));
  o[4] = __uint_as_float((unsigned int)x2); o[5] = __uint_as_float((unsigned int)(x2 >> 32));
  o[6] = __uint_as_float((unsigned int)x3); o[7] = __uint_as_float((unsigned int)(x3 >> 32));
}

__global__ __launch_bounds__(NTHR) void petri_kernel(
    const float* __restrict__ vsrc, const float* __restrict__ vtgt,
    const float* __restrict__ omg,  const float* __restrict__ W1,
    const float* __restrict__ b1,   const float* __restrict__ W2,
    const float* __restrict__ b2,   const float* __restrict__ W3,
    const float* __restrict__ b3,   const float* __restrict__ gum,
    ull* __restrict__ X, float* __restrict__ out) {
  __shared__ __half2 oh[64 * 512];   // 128 KB: {row2b[j], row2b+1[j]} per t
  __shared__ __align__(16) float A0_s[512];
  __shared__ __align__(16) float A1_s[512];
  __shared__ __align__(16) float v_loc[512];
  __shared__ float tgt_s[512];
  __shared__ float w1c_s[1024];      // W1 column b (both halves)
  __shared__ float gum_s[NSTEP * 64];
  __shared__ float b2_s[128], b3_s[64];
  __shared__ float soft_s[64], h1_s[256], h2_s[128];
  __shared__ float redp[512];
  __shared__ float llog[NSTEP * 64]; // deferred logits
  __shared__ float rf8[8];
  __shared__ int   ri8[8];
  __shared__ float cB_s[1];
  __shared__ int   bc[1];

  const int b = blockIdx.x, tid = threadIdx.x;
  const int wv = tid >> 6, ln = tid & 63;

  v_loc[tid] = vsrc[tid];
  tgt_s[tid] = vtgt[tid];
  w1c_s[tid] = W1[tid * 256 + b];
  w1c_s[tid + 512] = W1[(tid + 512) * 256 + b];
  for (int i = tid; i < NSTEP * 64; i += NTHR) gum_s[i] = gum[i];
  if (tid >= NTHR - 128) {
    int j = tid - (NTHR - 128);
    b2_s[j] = b2[j];
    if (j < 64) b3_s[j] = b3[j];
  }
  // W2 column slice in registers: thread (o=tid&127,q=tid>>7) holds
  // W2[(q*64+i)*128+o], i=0..63
  float w2r[64];
  {
    const int o = tid & 127, q = tid >> 7;
    const float* p = W2 + ((q << 6) * 128) + o;
#pragma unroll
    for (int i = 0; i < 64; ++i) w2r[i] = p[i * 128];
  }
  // W3 slice: thread (o=tid&63,q=tid>>6) holds W3[(q*16+i)*64+o], i=0..15
  float w3r[16];
  {
    const int o = tid & 63, q = tid >> 6;
    const float* p = W3 + ((q << 4) * 64) + o;
#pragma unroll
    for (int i = 0; i < 16; ++i) w3r[i] = p[i * 64];
  }
  // Omega rows 2b,2b+1 -> LDS fp16, float4-vectorized
  {
    const int tq = tid >> 7;            // 0..3 : t within group of 4
    const int c4 = (tid & 127) << 2;    // col 0..508 step 4
    const float* rp = omg + (b << 10) + c4;
#pragma unroll 4
    for (int g = 0; g < 16; ++g) {
      const int t = (g << 2) + tq;
      const float* p = rp + t * 262144;
      const float4 f0 = *(const float4*)(p);        // row 2b
      const float4 f1 = *(const float4*)(p + 512);  // row 2b+1
      __half2* dst = oh + t * 512 + c4;
      dst[0] = __floats2half2_rn(f0.x, f1.x);
      dst[1] = __floats2half2_rn(f0.y, f1.y);
      dst[2] = __floats2half2_rn(f0.z, f1.z);
      dst[3] = __floats2half2_rn(f0.w, f1.w);
    }
  }
  __syncthreads();

  // cB = b1[b] + dot(tgt, W1_bot[:,b])  -- off the per-step critical path
  {
    float p = tgt_s[tid] * w1c_s[tid + 512];
    p = wredsum(p);
    if (ln == 0) rf8[wv] = p;
    __syncthreads();
    if (tid == 0) {
      float a = b1[b];
      for (int q = 0; q < 8; ++q) a += rf8[q];
      cB_s[0] = a;
    }
    __syncthreads();
  }

  // target argmax (identical in every block), first-index tie-break
  int tgtIdx;
  {
    float v = tgt_s[tid]; int ix = tid;
#pragma unroll
    for (int off = 32; off > 0; off >>= 1) {
      float ov = __shfl_xor(v, off, 64); int oi = __shfl_xor(ix, off, 64);
      if (ov > v || (ov == v && oi < ix)) { v = ov; ix = oi; }
    }
    if (ln == 0) { rf8[wv] = v; ri8[wv] = ix; }
    __syncthreads();
    if (tid == 0) {
      float bv = rf8[0]; int bix = ri8[0];
      for (int q = 1; q < 8; ++q)
        if (rf8[q] > bv || (rf8[q] == bv && ri8[q] < bix)) { bv = rf8[q]; bix = ri8[q]; }
      bc[0] = bix;
    }
    __syncthreads();
    tgtIdx = bc[0];
    __syncthreads();
  }

  // wave0 register state: lane l owns vector elems 8l..8l+7 (= exchange
  // words 4l..4l+3) and the matching W1-top column slice.
  float vreg[8], w1t[8];
  if (wv == 0) {
    const int l8 = ln << 3;
#pragma unroll
    for (int k = 0; k < 8; ++k) { vreg[k] = v_loc[l8 + k]; w1t[k] = w1c_s[l8 + k]; }
    // startup: publish h1 of step 0 into round 0 (buf0, tag 0)
    float p = 0.f;
#pragma unroll
    for (int k = 0; k < 8; ++k) p = fmaf(vreg[k], w1t[k], p);
    p = wredsum(p);
    if (ln == 0) {
      float h = fmaxf(p + cB_s[0], 0.f);
      publish2(XW(0, b), h, h, 0u);
    }
  }

  int d = 0;
  int nAct = 0;  // number of active steps (uniform across blocks/threads)
  int r = 0;     // round counter: h1(s)=4s (buf0), T1/T2/T3 = 4s+1..3

  for (int s = 0; s < NSTEP; ++s) {
    if (d) continue;  // frozen (uniform across blocks); epilogue zero-fills
    nAct = s + 1;

    // ---- gather h1 (published at startup / in previous T3 tail) ----
    {
      const int buf = r & (RBUF - 1);
      const unsigned int tg = (unsigned int)((r >> 2) & 3);
      if (tid < 256) h1_s[tid] = poll2(XW(buf, tid), tg).x;
      __syncthreads();
      ++r;
    }

    // ---- replicated L2/L3/softmax from h1_s (register weights) ----
    {
      const int q = tid >> 7;
      const float* hp = h1_s + (q << 6);
      float a0 = 0.f, a1 = 0.f, a2 = 0.f, a3 = 0.f;
#pragma unroll
      for (int i = 0; i < 64; i += 4) {
        a0 = fmaf(hp[i],     w2r[i],     a0);
        a1 = fmaf(hp[i + 1], w2r[i + 1], a1);
        a2 = fmaf(hp[i + 2], w2r[i + 2], a2);
        a3 = fmaf(hp[i + 3], w2r[i + 3], a3);
      }
      redp[tid] = (a0 + a1) + (a2 + a3);
    }
    __syncthreads();
    if (tid < 128) {
      float rr = redp[tid] + redp[tid + 128] + redp[tid + 256] + redp[tid + 384] + b2_s[tid];
      h2_s[tid] = fmaxf(rr, 0.f);
    }
    __syncthreads();
    {
      const int q = tid >> 6;
      const float* hp = h2_s + (q << 4);
      float a0 = 0.f, a1 = 0.f;
#pragma unroll
      for (int i = 0; i < 16; i += 2) {
        a0 = fmaf(hp[i],     w3r[i],     a0);
        a1 = fmaf(hp[i + 1], w3r[i + 1], a1);
      }
      redp[tid] = a0 + a1;
    }
    __syncthreads();
    if (tid < 64) {
      float a = b3_s[tid];
#pragma unroll
      for (int q = 0; q < 8; ++q) a += redp[tid + (q << 6)];
      float lg = a + gum_s[s * 64 + tid];  // TAU = 1
      float mx = lg;
#pragma unroll
      for (int off = 32; off > 0; off >>= 1) mx = fmaxf(mx, __shfl_xor(mx, off, 64));
      float e = __expf(lg - mx);
      float sm = e;
#pragma unroll
      for (int off = 32; off > 0; off >>= 1) sm += __shfl_xor(sm, off, 64);
      soft_s[tid] = e / sm;
      llog[s * 64 + tid] = a;  // deferred logits
    }
    __syncthreads();

    // ---- mix 2 rows of A from LDS fp16 ----
    {
      float a0 = 0.f, a1 = 0.f, c0 = 0.f, c1 = 0.f;
#pragma unroll 8
      for (int t = 0; t < 64; t += 2) {
        float2 xy0 = __half22float2(oh[t * 512 + tid]);
        float2 xy1 = __half22float2(oh[(t + 1) * 512 + tid]);
        float s0 = soft_s[t], s1 = soft_s[t + 1];
        a0 = fmaf(s0, xy0.x, a0);
        c0 = fmaf(s0, xy0.y, c0);
        a1 = fmaf(s1, xy1.x, a1);
        c1 = fmaf(s1, xy1.y, c1);
      }
      A0_s[tid] = a0 + a1;
      A1_s[tid] = c0 + c1;
    }
    __syncthreads();

    // ---- rounds r..r+2: Taylor n=1..NTAY, wave0 solo, barrier-free.
    // T3 tail publishes h1(s+1) ~60ns after the vnew gather. ----
    if (wv == 0) {
      const int l8 = ln << 3;
      const float4 a00 = *(const float4*)(A0_s + l8);      // A row 2b
      const float4 a01 = *(const float4*)(A0_s + l8 + 4);
      const float4 a10 = *(const float4*)(A1_s + l8);      // A row 2b+1
      const float4 a11 = *(const float4*)(A1_s + l8 + 4);
      const float vb0 = v_loc[b << 1], vb1 = v_loc[(b << 1) + 1];
      float wreg[8];
#pragma unroll
      for (int k = 0; k < 8; ++k) wreg[k] = vreg[k];
      float acc0 = 0.f, acc1 = 0.f;
#pragma unroll
      for (int n = 1; n <= NTAY; ++n) {
        const int rr = r + (n - 1);
        const int buf = rr & (RBUF - 1);
        const unsigned int tg = (unsigned int)((rr >> 2) & 3);
        float p0 = 0.f, p1 = 0.f;
        p0 = fmaf(a00.x, wreg[0], p0); p0 = fmaf(a00.y, wreg[1], p0);
        p0 = fmaf(a00.z, wreg[2], p0); p0 = fmaf(a00.w, wreg[3], p0);
        p0 = fmaf(a01.x, wreg[4], p0); p0 = fmaf(a01.y, wreg[5], p0);
        p0 = fmaf(a01.z, wreg[6], p0); p0 = fmaf(a01.w, wreg[7], p0);
        p1 = fmaf(a10.x, wreg[0], p1); p1 = fmaf(a10.y, wreg[1], p1);
        p1 = fmaf(a10.z, wreg[2], p1); p1 = fmaf(a10.w, wreg[3], p1);
        p1 = fmaf(a11.x, wreg[4], p1); p1 = fmaf(a11.y, wreg[5], p1);
        p1 = fmaf(a11.z, wreg[6], p1); p1 = fmaf(a11.w, wreg[7], p1);
        wredsum2(p0, p1);
        if (ln == 0) {
          float s0, s1;
          if (n == 1) {
            s0 = p0; s1 = p1;
            acc0 = vb0 + s0; acc1 = vb1 + s1;
          } else {
            const float inv = (n == 2) ? 0.5f : (1.0f / 3.0f);
            s0 = p0 * inv; s1 = p1 * inv;
            acc0 += s0; acc1 += s1;
          }
          const float q0 = (n < NTAY) ? s0 : acc0;  // last round: vnew
          const float q1 = (n < NTAY) ? s1 : acc1;
          publish2(XW(buf, b), q0, q1, tg);
        }
        poll8(XW(buf, (ln << 2)), tg, wreg);
      }
      // h1(s+1) tail publish: round 4(s+1) (buf0, tag (s+1)&3). Safe by
      // induction: full gather of T1..T3(s) implies every block finished
      // reading buf0's h1(s).
      if (s + 1 < NSTEP) {
        const int rh = r + NTAY;
        const unsigned int tgh = (unsigned int)((rh >> 2) & 3);
        float ph = 0.f;
#pragma unroll
        for (int k = 0; k < 8; ++k) ph = fmaf(wreg[k], w1t[k], ph);
        ph = wredsum(ph);
        if (ln == 0) {
          float h = fmaxf(ph + cB_s[0], 0.f);
          publish2(XW(rh & (RBUF - 1), b), h, h, tgh);
        }
      }
      // vnew -> regs + LDS; solo argmax; done flag
#pragma unroll
      for (int k = 0; k < 8; ++k) vreg[k] = wreg[k];
      *(float4*)(v_loc + l8)     = make_float4(wreg[0], wreg[1], wreg[2], wreg[3]);
      *(float4*)(v_loc + l8 + 4) = make_float4(wreg[4], wreg[5], wreg[6], wreg[7]);
      float mv = wreg[0]; int mi = l8;
#pragma unroll
      for (int k = 1; k < 8; ++k) if (wreg[k] > mv) { mv = wreg[k]; mi = l8 + k; }
#pragma unroll
      for (int off = 32; off > 0; off >>= 1) {
        float ov = __shfl_xor(mv, off, 64); int oi = __shfl_xor(mi, off, 64);
        if (ov > mv || (ov == mv && oi < mi)) { mv = ov; mi = oi; }
      }
      if (ln == 0) bc[0] = (mi == tgtIdx) ? 1 : 0;
    }
    __syncthreads();
    if (bc[0]) d = 1;
    r += NTAY;
  }

  // ---- epilogue: all global writes (block 0 only) ----
  if (b == 0) {
    out[tid] = v_loc[tid];
    for (int i = tid; i < NSTEP * 64; i += NTHR)
      out[512 + i] = (i < nAct * 64) ? llog[i] : 0.0f;
  }
}

extern "C" void kernel_launch(void* const* d_in, const int* in_sizes, int n_in,
                              void* d_out, int out_size, void* d_ws, size_t ws_size,
                              hipStream_t stream) {
  (void)in_sizes; (void)n_in; (void)out_size; (void)ws_size;
  petri_kernel<<<dim3(NBLK), dim3(NTHR), 0, stream>>>(
      (const float*)d_in[0], (const float*)d_in[1], (const float*)d_in[2],
      (const float*)d_in[3], (const float*)d_in[4], (const float*)d_in[5],
      (const float*)d_in[6], (const float*)d_in[7], (const float*)d_in[8],
      (const float*)d_in[9], (ull*)d_ws, (float*)d_out);
}

// Round 10
// 319.350 us; speedup vs baseline: 1.0918x; 1.0401x over previous
//
#include <hip/hip_runtime.h>
#include <hip/hip_fp16.h>

// Persistent 256-block kernel (1 block/CU forced by ~155 KB LDS).
// Rows 2b,2b+1 of all 64 Omega_t cached ONCE in LDS as fp16 (validated
// R4-R8, absmax 0.0078). NTAY=3 Taylor terms of expm(A)@v.
//
// Exchange (fence-free): relaxed agent-scope 8-byte atomics only.
// TWO floats per word, tag in low-2 mantissa bits of float0 (one atom ->
// no ordering needed). 256 words per round, ONE PER 64B LINE (spread).
// 4 rotating buffers (64 KB d_ws): buf0 = h1, buf1/2/3 = T1/T2/T3; tags
// s&3. Skew induction: overwrite only after fully gathering the prior
// round -> distance-4/period-4-step reuse safe. Poison 0xAA low2=2 !=
// startup tag 0.
//
// ===== FINAL (R20): R17 restored; structure CONVERGED. =====
// Chain ledger @234us dispatch: 20 x (3 Taylor RTs ~7.0us + local
// MLP/softmax/mix ~2.5us + h1 poll-hit ~0.6us + barriers ~1.6us). The
// 2.3us RT is intrinsic (MALL visibility + 256-block spread): traffic
// shaping moved it <10% in 3 experiments. 3 RTs/step is algorithmic
// (3 sequential mat-vecs for Taylor expm).
// FAILED (counter-diagnosed): R12 890us atomicAdd h1-reduction (MALL RMW
// serialization). R13 292us packed exchange (publisher line contention).
// R14/R15/R16 1145-1202us register-file W1 (allocator pins 128 VGPR,
// ~1GB/dispatch scratch; macro-literal idx + waves_per_eu(2,2) both
// ineffective). R18 267us overlap-polled h1 (+256 polled words/block in
// the Taylor window -> +1.7us/step). R19 243us phase-aligned poll8
// (pre-sleep(40) lost the fast-RT tail the early sweeps caught).
// VERIFIED WINS: wave0-solo Taylor rounds (R11, -26us); h1 published in
// T3 tail -> poll-hit not RT (R17, -18us); deferred global stores via
// llog (R17); ILP'd MLP (R13); float4 omega staging (R11).

#define NBLK 256
#define NTHR 512
#define NSTEP 20
#define NTAY 3
#define RBUF 4

typedef unsigned long long ull;

// word i (i<256) of exchange buffer buf: 64 B apart (spread layout)
#define XW(buf, i) (X + ((((buf) << 8) + (i)) << 3))

__device__ __forceinline__ float wredsum(float p) {
#pragma unroll
  for (int off = 32; off > 0; off >>= 1) p += __shfl_xor(p, off, 64);
  return p;
}

__device__ __forceinline__ void wredsum2(float& p0, float& p1) {
#pragma unroll
  for (int off = 32; off > 0; off >>= 1) {
    float t0 = __shfl_xor(p0, off, 64);
    float t1 = __shfl_xor(p1, off, 64);
    p0 += t0;
    p1 += t1;
  }
}

__device__ __forceinline__ void publish2(ull* w, float v0, float v1, unsigned int tag2) {
  unsigned int u0 = (__float_as_uint(v0) & ~3u) | tag2;
  ull x = (ull)u0 | ((ull)__float_as_uint(v1) << 32);
  __hip_atomic_store(w, x, __ATOMIC_RELAXED, __HIP_MEMORY_SCOPE_AGENT);
}

__device__ __forceinline__ float2 poll2(ull* w, unsigned int tag2) {
  int it = 0;
  for (;;) {
    ull x = __hip_atomic_load(w, __ATOMIC_RELAXED, __HIP_MEMORY_SCOPE_AGENT);
    if ((unsigned int)(x & 3u) == tag2) {
      float2 r;
      r.x = __uint_as_float((unsigned int)x);
      r.y = __uint_as_float((unsigned int)(x >> 32));
      return r;
    }
    if (it == 0)      __builtin_amdgcn_s_sleep(1);
    else if (it == 1) __builtin_amdgcn_s_sleep(2);
    else              __builtin_amdgcn_s_sleep(4);
    if (it < 2) ++it;
  }
}

// lane-quad poll: 4 words (64 B apart) -> 8 floats; all 4 loads kept in
// flight per retry iteration (hand-unrolled, no runtime-indexed arrays).
// Schedule 1/2/4 (R11, verified best): early sweeps catch the fast-RT
// tail; R19's pre-sleep(40) regressed +9us.
__device__ __forceinline__ void poll8(ull* w0, unsigned int tg, float* o) {
  ull x0 = 0, x1 = 0, x2 = 0, x3 = 0;
  bool g0 = false, g1 = false, g2 = false, g3 = false;
  int it = 0;
  for (;;) {
    if (!g0) { ull x = __hip_atomic_load(w0,      __ATOMIC_RELAXED, __HIP_MEMORY_SCOPE_AGENT); if ((unsigned int)(x & 3u) == tg) { x0 = x; g0 = true; } }
    if (!g1) { ull x = __hip_atomic_load(w0 + 8,  __ATOMIC_RELAXED, __HIP_MEMORY_SCOPE_AGENT); if ((unsigned int)(x & 3u) == tg) { x1 = x; g1 = true; } }
    if (!g2) { ull x = __hip_atomic_load(w0 + 16, __ATOMIC_RELAXED, __HIP_MEMORY_SCOPE_AGENT); if ((unsigned int)(x & 3u) == tg) { x2 = x; g2 = true; } }
    if (!g3) { ull x = __hip_atomic_load(w0 + 24, __ATOMIC_RELAXED, __HIP_MEMORY_SCOPE_AGENT); if ((unsigned int)(x & 3u) == tg) { x3 = x; g3 = true; } }
    if (g0 && g1 && g2 && g3) break;
    if (it == 0)      __builtin_amdgcn_s_sleep(1);
    else if (it == 1) __builtin_amdgcn_s_sleep(2);
    else              __builtin_amdgcn_s_sleep(4);
    if (it < 2) ++it;
  }
  o[0] = __uint_as_float((unsigned int)x0); o[1] = __uint_as_float((unsigned int)(x0 >> 32));
  o[2] = __uint_as_float((unsigned int)x1); o[3] = __uint_as_float((unsigned int)(x1 >> 32));
  o[4] = __uint_as_float((unsigned int)x2); o[5] = __uint_as_float((unsigned int)(x2 >> 32));
  o[6] = __uint_as_float((unsigned int)x3); o[7] = __uint_as_float((unsigned int)(x3 >> 32));
}

__global__ __launch_bounds__(NTHR) void petri_kernel(
    const float* __restrict__ vsrc, const float* __restrict__ vtgt,
    const float* __restrict__ omg,  const float* __restrict__ W1,
    const float* __restrict__ b1,   const float* __restrict__ W2,
    const float* __restrict__ b2,   const float* __restrict__ W3,
    const float* __restrict__ b3,   const float* __restrict__ gum,
    ull* __restrict__ X, float* __restrict__ out) {
  __shared__ __half2 oh[64 * 512];   // 128 KB: {row2b[j], row2b+1[j]} per t
  __shared__ __align__(16) float A0_s[512];
  __shared__ __align__(16) float A1_s[512];
  __shared__ __align__(16) float v_loc[512];
  __shared__ float tgt_s[512];
  __shared__ float w1c_s[1024];      // W1 column b (both halves)
  __shared__ float gum_s[NSTEP * 64];
  __shared__ float b2_s[128], b3_s[64];
  __shared__ float soft_s[64], h1_s[256], h2_s[128];
  __shared__ float redp[512];
  __shared__ float llog[NSTEP * 64]; // deferred logits
  __shared__ float rf8[8];
  __shared__ int   ri8[8];
  __shared__ float cB_s[1];
  __shared__ int   bc[1];

  const int b = blockIdx.x, tid = threadIdx.x;
  const int wv = tid >> 6, ln = tid & 63;

  v_loc[tid] = vsrc[tid];
  tgt_s[tid] = vtgt[tid];
  w1c_s[tid] = W1[tid * 256 + b];
  w1c_s[tid + 512] = W1[(tid + 512) * 256 + b];
  for (int i = tid; i < NSTEP * 64; i += NTHR) gum_s[i] = gum[i];
  if (tid >= NTHR - 128) {
    int j = tid - (NTHR - 128);
    b2_s[j] = b2[j];
    if (j < 64) b3_s[j] = b3[j];
  }
  // W2 column slice in registers: thread (o=tid&127,q=tid>>7) holds
  // W2[(q*64+i)*128+o], i=0..63
  float w2r[64];
  {
    const int o = tid & 127, q = tid >> 7;
    const float* p = W2 + ((q << 6) * 128) + o;
#pragma unroll
    for (int i = 0; i < 64; ++i) w2r[i] = p[i * 128];
  }
  // W3 slice: thread (o=tid&63,q=tid>>6) holds W3[(q*16+i)*64+o], i=0..15
  float w3r[16];
  {
    const int o = tid & 63, q = tid >> 6;
    const float* p = W3 + ((q << 4) * 64) + o;
#pragma unroll
    for (int i = 0; i < 16; ++i) w3r[i] = p[i * 64];
  }
  // Omega rows 2b,2b+1 -> LDS fp16, float4-vectorized
  {
    const int tq = tid >> 7;            // 0..3 : t within group of 4
    const int c4 = (tid & 127) << 2;    // col 0..508 step 4
    const float* rp = omg + (b << 10) + c4;
#pragma unroll 4
    for (int g = 0; g < 16; ++g) {
      const int t = (g << 2) + tq;
      const float* p = rp + t * 262144;
      const float4 f0 = *(const float4*)(p);        // row 2b
      const float4 f1 = *(const float4*)(p + 512);  // row 2b+1
      __half2* dst = oh + t * 512 + c4;
      dst[0] = __floats2half2_rn(f0.x, f1.x);
      dst[1] = __floats2half2_rn(f0.y, f1.y);
      dst[2] = __floats2half2_rn(f0.z, f1.z);
      dst[3] = __floats2half2_rn(f0.w, f1.w);
    }
  }
  __syncthreads();

  // cB = b1[b] + dot(tgt, W1_bot[:,b])  -- off the per-step critical path
  {
    float p = tgt_s[tid] * w1c_s[tid + 512];
    p = wredsum(p);
    if (ln == 0) rf8[wv] = p;
    __syncthreads();
    if (tid == 0) {
      float a = b1[b];
      for (int q = 0; q < 8; ++q) a += rf8[q];
      cB_s[0] = a;
    }
    __syncthreads();
  }

  // target argmax (identical in every block), first-index tie-break
  int tgtIdx;
  {
    float v = tgt_s[tid]; int ix = tid;
#pragma unroll
    for (int off = 32; off > 0; off >>= 1) {
      float ov = __shfl_xor(v, off, 64); int oi = __shfl_xor(ix, off, 64);
      if (ov > v || (ov == v && oi < ix)) { v = ov; ix = oi; }
    }
    if (ln == 0) { rf8[wv] = v; ri8[wv] = ix; }
    __syncthreads();
    if (tid == 0) {
      float bv = rf8[0]; int bix = ri8[0];
      for (int q = 1; q < 8; ++q)
        if (rf8[q] > bv || (rf8[q] == bv && ri8[q] < bix)) { bv = rf8[q]; bix = ri8[q]; }
      bc[0] = bix;
    }
    __syncthreads();
    tgtIdx = bc[0];
    __syncthreads();
  }

  // wave0 register state: lane l owns vector elems 8l..8l+7 (= exchange
  // words 4l..4l+3) and the matching W1-top column slice.
  float vreg[8], w1t[8];
  if (wv == 0) {
    const int l8 = ln << 3;
#pragma unroll
    for (int k = 0; k < 8; ++k) { vreg[k] = v_loc[l8 + k]; w1t[k] = w1c_s[l8 + k]; }
    // startup: publish h1 of step 0 into round 0 (buf0, tag 0)
    float p = 0.f;
#pragma unroll
    for (int k = 0; k < 8; ++k) p = fmaf(vreg[k], w1t[k], p);
    p = wredsum(p);
    if (ln == 0) {
      float h = fmaxf(p + cB_s[0], 0.f);
      publish2(XW(0, b), h, h, 0u);
    }
  }

  int d = 0;
  int nAct = 0;  // number of active steps (uniform across blocks/threads)
  int r = 0;     // round counter: h1(s)=4s (buf0), T1/T2/T3 = 4s+1..3

  for (int s = 0; s < NSTEP; ++s) {
    if (d) continue;  // frozen (uniform across blocks); epilogue zero-fills
    nAct = s + 1;

    // ---- gather h1 (published at startup / in previous T3 tail) ----
    {
      const int buf = r & (RBUF - 1);
      const unsigned int tg = (unsigned int)((r >> 2) & 3);
      if (tid < 256) h1_s[tid] = poll2(XW(buf, tid), tg).x;
      __syncthreads();
      ++r;
    }

    // ---- replicated L2/L3/softmax from h1_s (register weights) ----
    {
      const int q = tid >> 7;
      const float* hp = h1_s + (q << 6);
      float a0 = 0.f, a1 = 0.f, a2 = 0.f, a3 = 0.f;
#pragma unroll
      for (int i = 0; i < 64; i += 4) {
        a0 = fmaf(hp[i],     w2r[i],     a0);
        a1 = fmaf(hp[i + 1], w2r[i + 1], a1);
        a2 = fmaf(hp[i + 2], w2r[i + 2], a2);
        a3 = fmaf(hp[i + 3], w2r[i + 3], a3);
      }
      redp[tid] = (a0 + a1) + (a2 + a3);
    }
    __syncthreads();
    if (tid < 128) {
      float rr = redp[tid] + redp[tid + 128] + redp[tid + 256] + redp[tid + 384] + b2_s[tid];
      h2_s[tid] = fmaxf(rr, 0.f);
    }
    __syncthreads();
    {
      const int q = tid >> 6;
      const float* hp = h2_s + (q << 4);
      float a0 = 0.f, a1 = 0.f;
#pragma unroll
      for (int i = 0; i < 16; i += 2) {
        a0 = fmaf(hp[i],     w3r[i],     a0);
        a1 = fmaf(hp[i + 1], w3r[i + 1], a1);
      }
      redp[tid] = a0 + a1;
    }
    __syncthreads();
    if (tid < 64) {
      float a = b3_s[tid];
#pragma unroll
      for (int q = 0; q < 8; ++q) a += redp[tid + (q << 6)];
      float lg = a + gum_s[s * 64 + tid];  // TAU = 1
      float mx = lg;
#pragma unroll
      for (int off = 32; off > 0; off >>= 1) mx = fmaxf(mx, __shfl_xor(mx, off, 64));
      float e = __expf(lg - mx);
      float sm = e;
#pragma unroll
      for (int off = 32; off > 0; off >>= 1) sm += __shfl_xor(sm, off, 64);
      soft_s[tid] = e / sm;
      llog[s * 64 + tid] = a;  // deferred logits
    }
    __syncthreads();

    // ---- mix 2 rows of A from LDS fp16 ----
    {
      float a0 = 0.f, a1 = 0.f, c0 = 0.f, c1 = 0.f;
#pragma unroll 8
      for (int t = 0; t < 64; t += 2) {
        float2 xy0 = __half22float2(oh[t * 512 + tid]);
        float2 xy1 = __half22float2(oh[(t + 1) * 512 + tid]);
        float s0 = soft_s[t], s1 = soft_s[t + 1];
        a0 = fmaf(s0, xy0.x, a0);
        c0 = fmaf(s0, xy0.y, c0);
        a1 = fmaf(s1, xy1.x, a1);
        c1 = fmaf(s1, xy1.y, c1);
      }
      A0_s[tid] = a0 + a1;
      A1_s[tid] = c0 + c1;
    }
    __syncthreads();

    // ---- rounds r..r+2: Taylor n=1..NTAY, wave0 solo, barrier-free.
    // T3 tail publishes h1(s+1) ~60ns after the vnew gather. ----
    if (wv == 0) {
      const int l8 = ln << 3;
      const float4 a00 = *(const float4*)(A0_s + l8);      // A row 2b
      const float4 a01 = *(const float4*)(A0_s + l8 + 4);
      const float4 a10 = *(const float4*)(A1_s + l8);      // A row 2b+1
      const float4 a11 = *(const float4*)(A1_s + l8 + 4);
      const float vb0 = v_loc[b << 1], vb1 = v_loc[(b << 1) + 1];
      float wreg[8];
#pragma unroll
      for (int k = 0; k < 8; ++k) wreg[k] = vreg[k];
      float acc0 = 0.f, acc1 = 0.f;
#pragma unroll
      for (int n = 1; n <= NTAY; ++n) {
        const int rr = r + (n - 1);
        const int buf = rr & (RBUF - 1);
        const unsigned int tg = (unsigned int)((rr >> 2) & 3);
        float p0 = 0.f, p1 = 0.f;
        p0 = fmaf(a00.x, wreg[0], p0); p0 = fmaf(a00.y, wreg[1], p0);
        p0 = fmaf(a00.z, wreg[2], p0); p0 = fmaf(a00.w, wreg[3], p0);
        p0 = fmaf(a01.x, wreg[4], p0); p0 = fmaf(a01.y, wreg[5], p0);
        p0 = fmaf(a01.z, wreg[6], p0); p0 = fmaf(a01.w, wreg[7], p0);
        p1 = fmaf(a10.x, wreg[0], p1); p1 = fmaf(a10.y, wreg[1], p1);
        p1 = fmaf(a10.z, wreg[2], p1); p1 = fmaf(a10.w, wreg[3], p1);
        p1 = fmaf(a11.x, wreg[4], p1); p1 = fmaf(a11.y, wreg[5], p1);
        p1 = fmaf(a11.z, wreg[6], p1); p1 = fmaf(a11.w, wreg[7], p1);
        wredsum2(p0, p1);
        if (ln == 0) {
          float s0, s1;
          if (n == 1) {
            s0 = p0; s1 = p1;
            acc0 = vb0 + s0; acc1 = vb1 + s1;
          } else {
            const float inv = (n == 2) ? 0.5f : (1.0f / 3.0f);
            s0 = p0 * inv; s1 = p1 * inv;
            acc0 += s0; acc1 += s1;
          }
          const float q0 = (n < NTAY) ? s0 : acc0;  // last round: vnew
          const float q1 = (n < NTAY) ? s1 : acc1;
          publish2(XW(buf, b), q0, q1, tg);
        }
        poll8(XW(buf, (ln << 2)), tg, wreg);
      }
      // h1(s+1) tail publish: round 4(s+1) (buf0, tag (s+1)&3). Safe by
      // induction: full gather of T1..T3(s) implies every block finished
      // reading buf0's h1(s).
      if (s + 1 < NSTEP) {
        const int rh = r + NTAY;
        const unsigned int tgh = (unsigned int)((rh >> 2) & 3);
        float ph = 0.f;
#pragma unroll
        for (int k = 0; k < 8; ++k) ph = fmaf(wreg[k], w1t[k], ph);
        ph = wredsum(ph);
        if (ln == 0) {
          float h = fmaxf(ph + cB_s[0], 0.f);
          publish2(XW(rh & (RBUF - 1), b), h, h, tgh);
        }
      }
      // vnew -> regs + LDS; solo argmax; done flag
#pragma unroll
      for (int k = 0; k < 8; ++k) vreg[k] = wreg[k];
      *(float4*)(v_loc + l8)     = make_float4(wreg[0], wreg[1], wreg[2], wreg[3]);
      *(float4*)(v_loc + l8 + 4) = make_float4(wreg[4], wreg[5], wreg[6], wreg[7]);
      float mv = wreg[0]; int mi = l8;
#pragma unroll
      for (int k = 1; k < 8; ++k) if (wreg[k] > mv) { mv = wreg[k]; mi = l8 + k; }
#pragma unroll
      for (int off = 32; off > 0; off >>= 1) {
        float ov = __shfl_xor(mv, off, 64); int oi = __shfl_xor(mi, off, 64);
        if (ov > mv || (ov == mv && oi < mi)) { mv = ov; mi = oi; }
      }
      if (ln == 0) bc[0] = (mi == tgtIdx) ? 1 : 0;
    }
    __syncthreads();
    if (bc[0]) d = 1;
    r += NTAY;
  }

  // ---- epilogue: all global writes (block 0 only) ----
  if (b == 0) {
    out[tid] = v_loc[tid];
    for (int i = tid; i < NSTEP * 64; i += NTHR)
      out[512 + i] = (i < nAct * 64) ? llog[i] : 0.0f;
  }
}

extern "C" void kernel_launch(void* const* d_in, const int* in_sizes, int n_in,
                              void* d_out, int out_size, void* d_ws, size_t ws_size,
                              hipStream_t stream) {
  (void)in_sizes; (void)n_in; (void)out_size; (void)ws_size;
  petri_kernel<<<dim3(NBLK), dim3(NTHR), 0, stream>>>(
      (const float*)d_in[0], (const float*)d_in[1], (const float*)d_in[2],
      (const float*)d_in[3], (const float*)d_in[4], (const float*)d_in[5],
      (const float*)d_in[6], (const float*)d_in[7], (const float*)d_in[8],
      (const float*)d_in[9], (ull*)d_ws, (float*)d_out);
}